// Round 5
// baseline (2560.170 us; speedup 1.0000x reference)
//
#include <hip/hip_runtime.h>
#include <hip/hip_bf16.h>
#include <math.h>

#define B_   512
#define H_   512
#define FIN_ 1024
#define TS_  128

typedef __attribute__((ext_vector_type(8))) short short8;
typedef __attribute__((ext_vector_type(4))) float f32x4;

static __device__ __forceinline__ short f2bf(float f) {
    __hip_bfloat16 b = __float2bfloat16(f);
    return __builtin_bit_cast(short, b);
}
static __device__ __forceinline__ float bf2f(short s) {
    unsigned int u = ((unsigned int)(unsigned short)s) << 16;
    return __builtin_bit_cast(float, u);
}

// ---------------- weight prepack (once per call) ----------------
// Wpk2 fragment-packed bf16 pairs:
//   [jt 0..31][kt 0..15][g 0..5][sel 0..1 (hi/lo)][lane 0..63][i 0..7]
// B-frag (16x16x32): lane holds B[k = kt*32 + (lane>>4)*8 + i][j = jt*16 + (lane&15)]
__global__ __launch_bounds__(384)
void pack_weights(const float* __restrict__ Wih, const float* __restrict__ Whh,
                  short* __restrict__ Wpk2) {
    int jt = blockIdx.x;              // 0..31
    int kt = blockIdx.y;              // 0..15
    int g    = threadIdx.x >> 6;      // 0..5
    int lane = threadIdx.x & 63;
    int j = jt * 16 + (lane & 15);
    int k = kt * 32 + (lane >> 4) * 8;
    const float* src = (g < 3) ? &Wih[(size_t)(g * H_ + j) * H_ + k]
                               : &Whh[(size_t)((g - 3) * H_ + j) * H_ + k];
    short8 vhi, vlo;
#pragma unroll
    for (int i = 0; i < 8; ++i) {
        float w  = src[i];
        short hi = f2bf(w);
        vhi[i] = hi;
        vlo[i] = f2bf(w - bf2f(hi));
    }
    size_t base = ((((size_t)(jt * 16 + kt) * 6 + g) * 2) * 64 + lane) * 8;
    *reinterpret_cast<short8*>(&Wpk2[base])       = vhi;
    *reinterpret_cast<short8*>(&Wpk2[base + 512]) = vlo;
}

// WlinT[k][j] = W_lin[j][k], [1024][512]
__global__ void transpose_lin(const float* __restrict__ Wlin,
                              float* __restrict__ Wt) {
    __shared__ float t[32][33];
    int j0 = blockIdx.x * 32, k0 = blockIdx.y * 32;
    int kk = threadIdx.x, jj = threadIdx.y;
#pragma unroll
    for (int r = 0; r < 32; r += 8)
        t[jj + r][kk] = Wlin[(size_t)(j0 + jj + r) * FIN_ + k0 + kk];
    __syncthreads();
#pragma unroll
    for (int r = 0; r < 32; r += 8)
        Wt[(size_t)(k0 + jj + r) * H_ + j0 + kk] = t[kk][jj + r];
}

// ---------------- h0 = x @ WlinT + b_lin  (fp32, writes hi/lo bf16 split) ----------------
__global__ __launch_bounds__(256)
void gemm_h0(const float* __restrict__ X, const float* __restrict__ Wt,
             const float* __restrict__ bias,
             short* __restrict__ Hhi, short* __restrict__ Hlo) {
    const int BM = 32, BN = 32, BK = 32;
    __shared__ float xs[BK][BM + 2];
    __shared__ float ws[BK][BN];
    int b0 = blockIdx.y * BM, j0 = blockIdx.x * BN;
    int tid = threadIdx.x;
    int tx = tid & 15, ty = tid >> 4;
    float acc[2][2] = {};
    for (int k0 = 0; k0 < FIN_; k0 += BK) {
#pragma unroll
        for (int l = 0; l < 2; ++l) {
            int e = tid + l * 256;
            int krel = (e & 15) * 2, brel = e >> 4;
            float2 v = *(const float2*)&X[(size_t)(b0 + brel) * FIN_ + k0 + krel];
            xs[krel][brel] = v.x; xs[krel + 1][brel] = v.y;
        }
        {
            int fe = tid;
            int j4 = fe & 7, krel = fe >> 3;
            *(float4*)&ws[krel][j4 * 4] =
                *(const float4*)&Wt[(size_t)(k0 + krel) * H_ + j0 + j4 * 4];
        }
        __syncthreads();
#pragma unroll
        for (int kk = 0; kk < BK; ++kk) {
            float2 a = *(const float2*)&xs[kk][ty * 2];
            float2 w = *(const float2*)&ws[kk][tx * 2];
            acc[0][0] += a.x * w.x; acc[0][1] += a.x * w.y;
            acc[1][0] += a.y * w.x; acc[1][1] += a.y * w.y;
        }
        __syncthreads();
    }
#pragma unroll
    for (int r = 0; r < 2; ++r)
#pragma unroll
        for (int c = 0; c < 2; ++c) {
            int b = b0 + ty * 2 + r, j = j0 + tx * 2 + c;
            float v = acc[r][c] + bias[j];
            short hi = f2bf(v);
            Hhi[(size_t)b * H_ + j] = hi;
            Hlo[(size_t)b * H_ + j] = f2bf(v - bf2f(hi));
        }
}

// ---------------- persistent GRU: all 128 steps in one kernel ----------------
// 256 blocks (1/CU), 512 threads (8 waves). Block = (row-group m = bid&7 -> 64
// rows, jt = bid>>3 -> 16 cols). Wave w owns kt in {2w, 2w+1}; its W fragments
// (2 kt x 6 g x hi/lo = 96 VGPRs) stay in registers across all 128 steps.
// Per step: A loads (wave's kt slice of h), 144 MFMAs partials, split-K tree
// reduce in LDS, epilogue (gate math) by all waves, 32-block group barrier.
__global__ __launch_bounds__(512, 2)
void gru_persist(const short* __restrict__ Wpk2,
                 const float* __restrict__ bp,
                 short* __restrict__ hHiA, short* __restrict__ hLoA,
                 short* __restrict__ hHiB, short* __restrict__ hLoB,
                 float* __restrict__ out,
                 unsigned int* __restrict__ ctr) {
    int bid  = blockIdx.x;
    int m    = bid & 7;            // row group (8 groups x 64 rows)
    int jt   = bid >> 3;           // 0..31
    int m0   = m * 64;
    int tid  = threadIdx.x;
    int w    = tid >> 6;           // wave 0..7
    int lane = tid & 63;

    __shared__ float red[4][4][6][64][4];   // 4 bufs x 24 KB = 96 KB

    // ---- prologue: persistent W fragments ----
    short8 Wf[2][6][2];
#pragma unroll
    for (int kk = 0; kk < 2; ++kk) {
        int kt = 2 * w + kk;
        const short* wb = &Wpk2[((size_t)(jt * 16 + kt) * 6) * 1024 + lane * 8];
#pragma unroll
        for (int g = 0; g < 6; ++g) {
            Wf[kk][g][0] = *(const short8*)&wb[(size_t)g * 1024];
            Wf[kk][g][1] = *(const short8*)&wb[(size_t)g * 1024 + 512];
        }
    }

    // ---- epilogue mapping: thread handles 2 outputs (same row, adjacent cols) ----
    int o0   = tid * 2;
    int erow = o0 >> 4;            // 0..63 block-local row
    int ecol = o0 & 15;            // even col 0..14
    int gr   = m0 + erow;          // global row
    int gc0  = jt * 16 + ecol, gc1 = gc0 + 1;
    float eb0[6], eb1[6];
#pragma unroll
    for (int g = 0; g < 6; ++g) { eb0[g] = bp[g * H_ + gc0]; eb1[g] = bp[g * H_ + gc1]; }
    int emf   = erow >> 4;
    int elane = ((erow & 15) >> 2) << 4;
    int ev    = erow & 3;

    const short* curHi = hHiA; const short* curLo = hLoA;
    short* nxtHi = hHiB; short* nxtLo = hLoB;

    int arow  = m0 + (lane & 15);
    int akoff = (lane >> 4) * 8;

    for (int t = 0; t < TS_; ++t) {
        f32x4 acc[4][6] = {};
#pragma unroll
        for (int kk = 0; kk < 2; ++kk) {
            int kbase = (2 * w + kk) * 32 + akoff;
#pragma unroll
            for (int mf = 0; mf < 4; ++mf) {
                size_t aoff = (size_t)(arow + 16 * mf) * H_ + kbase;
                short8 ahi = *(const short8*)&curHi[aoff];
                short8 alo = *(const short8*)&curLo[aoff];
                if (t > 0) {
#pragma unroll
                    for (int g = 0; g < 3; ++g) {
                        acc[mf][g] = __builtin_amdgcn_mfma_f32_16x16x32_bf16(ahi, Wf[kk][g][0], acc[mf][g], 0, 0, 0);
                        acc[mf][g] = __builtin_amdgcn_mfma_f32_16x16x32_bf16(ahi, Wf[kk][g][1], acc[mf][g], 0, 0, 0);
                        acc[mf][g] = __builtin_amdgcn_mfma_f32_16x16x32_bf16(alo, Wf[kk][g][0], acc[mf][g], 0, 0, 0);
                    }
                }
#pragma unroll
                for (int g = 3; g < 6; ++g) {
                    acc[mf][g] = __builtin_amdgcn_mfma_f32_16x16x32_bf16(ahi, Wf[kk][g][0], acc[mf][g], 0, 0, 0);
                    acc[mf][g] = __builtin_amdgcn_mfma_f32_16x16x32_bf16(ahi, Wf[kk][g][1], acc[mf][g], 0, 0, 0);
                    acc[mf][g] = __builtin_amdgcn_mfma_f32_16x16x32_bf16(alo, Wf[kk][g][0], acc[mf][g], 0, 0, 0);
                }
            }
        }

        // ---- split-K tree reduction in LDS ----
        if (w >= 4) {
#pragma unroll
            for (int mf = 0; mf < 4; ++mf)
#pragma unroll
                for (int g = 0; g < 6; ++g)
                    *(f32x4*)&red[w - 4][mf][g][lane][0] = acc[mf][g];
        }
        __syncthreads();
        if (w < 4) {
#pragma unroll
            for (int mf = 0; mf < 4; ++mf)
#pragma unroll
                for (int g = 0; g < 6; ++g)
                    acc[mf][g] += *(const f32x4*)&red[w][mf][g][lane][0];
        }
        __syncthreads();
        if (w == 2 || w == 3) {
#pragma unroll
            for (int mf = 0; mf < 4; ++mf)
#pragma unroll
                for (int g = 0; g < 6; ++g)
                    *(f32x4*)&red[w - 2][mf][g][lane][0] = acc[mf][g];
        }
        __syncthreads();
        if (w < 2) {
#pragma unroll
            for (int mf = 0; mf < 4; ++mf)
#pragma unroll
                for (int g = 0; g < 6; ++g)
                    acc[mf][g] += *(const f32x4*)&red[w][mf][g][lane][0];
        }
        __syncthreads();
        if (w == 1) {
#pragma unroll
            for (int mf = 0; mf < 4; ++mf)
#pragma unroll
                for (int g = 0; g < 6; ++g)
                    *(f32x4*)&red[0][mf][g][lane][0] = acc[mf][g];
        }
        __syncthreads();
        if (w == 0) {
#pragma unroll
            for (int mf = 0; mf < 4; ++mf)
#pragma unroll
                for (int g = 0; g < 6; ++g) {
                    acc[mf][g] += *(const f32x4*)&red[0][mf][g][lane][0];
                    *(f32x4*)&red[1][mf][g][lane][0] = acc[mf][g];
                }
        }
        __syncthreads();

        // ---- epilogue: gate math, 2 outputs per thread ----
        {
            float v0[6], v1[6];
#pragma unroll
            for (int g = 0; g < 6; ++g) {
                v0[g] = red[1][emf][g][elane + ecol][ev];
                v1[g] = red[1][emf][g][elane + ecol + 1][ev];
            }
            size_t i0 = (size_t)gr * H_ + gc0;
            size_t i1 = (size_t)gr * H_ + gc1;
            float hp0 = bf2f(curHi[i0]) + bf2f(curLo[i0]);
            float hp1 = bf2f(curHi[i1]) + bf2f(curLo[i1]);

            float rg0 = 1.f / (1.f + expf(-((v0[0] + eb0[0]) + (v0[3] + eb0[3]))));
            float zg0 = 1.f / (1.f + expf(-((v0[1] + eb0[1]) + (v0[4] + eb0[4]))));
            float ng0 = tanhf((v0[2] + eb0[2]) + rg0 * (v0[5] + eb0[5]));
            float hn0 = (1.f - zg0) * ng0 + zg0 * hp0;

            float rg1 = 1.f / (1.f + expf(-((v1[0] + eb1[0]) + (v1[3] + eb1[3]))));
            float zg1 = 1.f / (1.f + expf(-((v1[1] + eb1[1]) + (v1[4] + eb1[4]))));
            float ng1 = tanhf((v1[2] + eb1[2]) + rg1 * (v1[5] + eb1[5]));
            float hn1 = (1.f - zg1) * ng1 + zg1 * hp1;

            short h0i = f2bf(hn0), h1i = f2bf(hn1);
            nxtHi[i0] = h0i; nxtLo[i0] = f2bf(hn0 - bf2f(h0i));
            nxtHi[i1] = h1i; nxtLo[i1] = f2bf(hn1 - bf2f(h1i));
            size_t oo = (size_t)gr * (TS_ * H_) + (size_t)t * H_;
            out[oo + gc0] = hn0;
            out[oo + gc1] = hn1;
        }

        __syncthreads();   // all stores issued & drained before release

        if (t < TS_ - 1) {
            if (tid == 0) {
                __hip_atomic_fetch_add(&ctr[m], 1u, __ATOMIC_RELEASE, __HIP_MEMORY_SCOPE_AGENT);
                unsigned int target = 32u * (unsigned)(t + 1);
                while (__hip_atomic_load(&ctr[m], __ATOMIC_ACQUIRE, __HIP_MEMORY_SCOPE_AGENT) < target)
                    __builtin_amdgcn_s_sleep(2);
            }
            __syncthreads();
            const short* th = curHi; const short* tl = curLo;
            curHi = nxtHi; curLo = nxtLo;
            nxtHi = (short*)th; nxtLo = (short*)tl;
        }
    }
}

extern "C" void kernel_launch(void* const* d_in, const int* in_sizes, int n_in,
                              void* d_out, int out_size, void* d_ws, size_t ws_size,
                              hipStream_t stream) {
    const float* x     = (const float*)d_in[0];
    const float* W_lin = (const float*)d_in[1];
    const float* b_lin = (const float*)d_in[2];
    const float* W_ih  = (const float*)d_in[3];
    const float* W_hh  = (const float*)d_in[4];
    const float* b_ih  = (const float*)d_in[5];
    const float* b_hh  = (const float*)d_in[6];
    float* out = (float*)d_out;

    char* wsb = (char*)d_ws;
    short* Wpk2  = (short*)(wsb);                    // 6291456 B
    float* WlinT = (float*)(wsb + 6291456);          // 2097152 B
    float* bp    = (float*)(wsb + 8388608);          // 12288 B
    short* hHiA  = (short*)(wsb + 8400896);          // 524288 B
    short* hLoA  = (short*)(wsb + 8925184);
    short* hHiB  = (short*)(wsb + 9449472);
    short* hLoB  = (short*)(wsb + 9973760);
    unsigned int* ctr = (unsigned int*)(wsb + 10498048);  // 8 uints

    hipMemcpyAsync(bp,        b_ih, 1536 * sizeof(float), hipMemcpyDeviceToDevice, stream);
    hipMemcpyAsync(bp + 1536, b_hh, 1536 * sizeof(float), hipMemcpyDeviceToDevice, stream);
    hipMemsetAsync(ctr, 0, 8 * sizeof(unsigned int), stream);

    pack_weights <<<dim3(32, 16), 384, 0, stream>>>(W_ih, W_hh, Wpk2);
    transpose_lin<<<dim3(16, 32), dim3(32, 8), 0, stream>>>(W_lin, WlinT);

    gemm_h0<<<dim3(16, 16), 256, 0, stream>>>(x, WlinT, b_lin, hHiA, hLoA);

    gru_persist<<<256, 512, 0, stream>>>(Wpk2, bp, hHiA, hLoA, hHiB, hLoB, out, ctr);
}

// Round 6
// 2109.538 us; speedup vs baseline: 1.2136x; 1.2136x over previous
//
#include <hip/hip_runtime.h>
#include <hip/hip_bf16.h>
#include <math.h>

#define B_   512
#define H_   512
#define FIN_ 1024
#define TS_  128

typedef __attribute__((ext_vector_type(8))) short short8;
typedef __attribute__((ext_vector_type(4))) float f32x4;

static __device__ __forceinline__ short f2bf(float f) {
    __hip_bfloat16 b = __float2bfloat16(f);
    return __builtin_bit_cast(short, b);
}
static __device__ __forceinline__ float bf2f(short s) {
    unsigned int u = ((unsigned int)(unsigned short)s) << 16;
    return __builtin_bit_cast(float, u);
}

// ---------------- weight prepack (once per call) ----------------
// Wpk2 fragment-packed bf16 pairs:
//   [jt 0..31][kt 0..15][g 0..5][sel 0..1 (hi/lo)][lane 0..63][i 0..7]
// B-frag (16x16x32): lane holds B[k = kt*32 + (lane>>4)*8 + i][j = jt*16 + (lane&15)]
__global__ __launch_bounds__(384)
void pack_weights(const float* __restrict__ Wih, const float* __restrict__ Whh,
                  short* __restrict__ Wpk2) {
    int jt = blockIdx.x;              // 0..31
    int kt = blockIdx.y;              // 0..15
    int g    = threadIdx.x >> 6;      // 0..5
    int lane = threadIdx.x & 63;
    int j = jt * 16 + (lane & 15);
    int k = kt * 32 + (lane >> 4) * 8;
    const float* src = (g < 3) ? &Wih[(size_t)(g * H_ + j) * H_ + k]
                               : &Whh[(size_t)((g - 3) * H_ + j) * H_ + k];
    short8 vhi, vlo;
#pragma unroll
    for (int i = 0; i < 8; ++i) {
        float w  = src[i];
        short hi = f2bf(w);
        vhi[i] = hi;
        vlo[i] = f2bf(w - bf2f(hi));
    }
    size_t base = ((((size_t)(jt * 16 + kt) * 6 + g) * 2) * 64 + lane) * 8;
    *reinterpret_cast<short8*>(&Wpk2[base])       = vhi;
    *reinterpret_cast<short8*>(&Wpk2[base + 512]) = vlo;
}

// WlinT[k][j] = W_lin[j][k], [1024][512]
__global__ void transpose_lin(const float* __restrict__ Wlin,
                              float* __restrict__ Wt) {
    __shared__ float t[32][33];
    int j0 = blockIdx.x * 32, k0 = blockIdx.y * 32;
    int kk = threadIdx.x, jj = threadIdx.y;
#pragma unroll
    for (int r = 0; r < 32; r += 8)
        t[jj + r][kk] = Wlin[(size_t)(j0 + jj + r) * FIN_ + k0 + kk];
    __syncthreads();
#pragma unroll
    for (int r = 0; r < 32; r += 8)
        Wt[(size_t)(k0 + jj + r) * H_ + j0 + kk] = t[kk][jj + r];
}

// ---------------- h0 = x @ WlinT + b_lin  (fp32, writes hi/lo bf16 split) ----------------
__global__ __launch_bounds__(256)
void gemm_h0(const float* __restrict__ X, const float* __restrict__ Wt,
             const float* __restrict__ bias,
             short* __restrict__ Hhi, short* __restrict__ Hlo) {
    const int BM = 32, BN = 32, BK = 32;
    __shared__ float xs[BK][BM + 2];
    __shared__ float ws[BK][BN];
    int b0 = blockIdx.y * BM, j0 = blockIdx.x * BN;
    int tid = threadIdx.x;
    int tx = tid & 15, ty = tid >> 4;
    float acc[2][2] = {};
    for (int k0 = 0; k0 < FIN_; k0 += BK) {
#pragma unroll
        for (int l = 0; l < 2; ++l) {
            int e = tid + l * 256;
            int krel = (e & 15) * 2, brel = e >> 4;
            float2 v = *(const float2*)&X[(size_t)(b0 + brel) * FIN_ + k0 + krel];
            xs[krel][brel] = v.x; xs[krel + 1][brel] = v.y;
        }
        {
            int fe = tid;
            int j4 = fe & 7, krel = fe >> 3;
            *(float4*)&ws[krel][j4 * 4] =
                *(const float4*)&Wt[(size_t)(k0 + krel) * H_ + j0 + j4 * 4];
        }
        __syncthreads();
#pragma unroll
        for (int kk = 0; kk < BK; ++kk) {
            float2 a = *(const float2*)&xs[kk][ty * 2];
            float2 w = *(const float2*)&ws[kk][tx * 2];
            acc[0][0] += a.x * w.x; acc[0][1] += a.x * w.y;
            acc[1][0] += a.y * w.x; acc[1][1] += a.y * w.y;
        }
        __syncthreads();
    }
#pragma unroll
    for (int r = 0; r < 2; ++r)
#pragma unroll
        for (int c = 0; c < 2; ++c) {
            int b = b0 + ty * 2 + r, j = j0 + tx * 2 + c;
            float v = acc[r][c] + bias[j];
            short hi = f2bf(v);
            Hhi[(size_t)b * H_ + j] = hi;
            Hlo[(size_t)b * H_ + j] = f2bf(v - bf2f(hi));
        }
}

// ---------------- persistent GRU: all 128 steps in one kernel ----------------
// 256 blocks (1/CU), 512 threads (8 waves). Block = (row-group m = bid&7 -> 64
// rows, jt = bid>>3 -> 16 cols). Blocks of one group share bid%8 -> likely one
// XCD (perf-only assumption; correctness via AGENT-scope release/acquire).
// Wave w owns kt in {2w, 2w+1}; W fragments persist in VGPRs across all steps.
// Barrier: padded per-group counter (1024B apart), RELAXED polling + single
// ACQUIRE, release via one fetch_add per block.
__global__ __launch_bounds__(512, 2)
void gru_persist(const short* __restrict__ Wpk2,
                 const float* __restrict__ bp,
                 short* __restrict__ hHiA, short* __restrict__ hLoA,
                 short* __restrict__ hHiB, short* __restrict__ hLoB,
                 float* __restrict__ out,
                 unsigned int* __restrict__ ctr) {
    int bid  = blockIdx.x;
    int m    = bid & 7;            // row group (8 groups x 64 rows)
    int jt   = bid >> 3;           // 0..31
    int m0   = m * 64;
    int tid  = threadIdx.x;
    int w    = tid >> 6;           // wave 0..7
    int lane = tid & 63;

    unsigned int* myctr = ctr + m * 256;   // 1024B-spaced counters (no false sharing)

    __shared__ float red[4][4][6][64][4];   // 4 bufs x 24 KB = 96 KB

    // ---- prologue: persistent W fragments ----
    short8 Wf[2][6][2];
#pragma unroll
    for (int kk = 0; kk < 2; ++kk) {
        int kt = 2 * w + kk;
        const short* wb = &Wpk2[((size_t)(jt * 16 + kt) * 6) * 1024 + lane * 8];
#pragma unroll
        for (int g = 0; g < 6; ++g) {
            Wf[kk][g][0] = *(const short8*)&wb[(size_t)g * 1024];
            Wf[kk][g][1] = *(const short8*)&wb[(size_t)g * 1024 + 512];
        }
    }

    // ---- epilogue mapping: thread handles 2 outputs (same row, adjacent cols) ----
    int o0   = tid * 2;
    int erow = o0 >> 4;            // 0..63 block-local row
    int ecol = o0 & 15;            // even col 0..14
    int gr   = m0 + erow;          // global row
    int gc0  = jt * 16 + ecol, gc1 = gc0 + 1;
    float eb0[6], eb1[6];
#pragma unroll
    for (int g = 0; g < 6; ++g) { eb0[g] = bp[g * H_ + gc0]; eb1[g] = bp[g * H_ + gc1]; }
    int emf   = erow >> 4;
    int elane = ((erow & 15) >> 2) << 4;
    int ev    = erow & 3;

    const short* curHi = hHiA; const short* curLo = hLoA;
    short* nxtHi = hHiB; short* nxtLo = hLoB;

    int arow  = m0 + (lane & 15);
    int akoff = (lane >> 4) * 8;

    for (int t = 0; t < TS_; ++t) {
        f32x4 acc[4][6] = {};
#pragma unroll
        for (int kk = 0; kk < 2; ++kk) {
            int kbase = (2 * w + kk) * 32 + akoff;
#pragma unroll
            for (int mf = 0; mf < 4; ++mf) {
                size_t aoff = (size_t)(arow + 16 * mf) * H_ + kbase;
                short8 ahi = *(const short8*)&curHi[aoff];
                short8 alo = *(const short8*)&curLo[aoff];
                if (t > 0) {
#pragma unroll
                    for (int g = 0; g < 3; ++g) {
                        acc[mf][g] = __builtin_amdgcn_mfma_f32_16x16x32_bf16(ahi, Wf[kk][g][0], acc[mf][g], 0, 0, 0);
                        acc[mf][g] = __builtin_amdgcn_mfma_f32_16x16x32_bf16(ahi, Wf[kk][g][1], acc[mf][g], 0, 0, 0);
                        acc[mf][g] = __builtin_amdgcn_mfma_f32_16x16x32_bf16(alo, Wf[kk][g][0], acc[mf][g], 0, 0, 0);
                    }
                }
#pragma unroll
                for (int g = 3; g < 6; ++g) {
                    acc[mf][g] = __builtin_amdgcn_mfma_f32_16x16x32_bf16(ahi, Wf[kk][g][0], acc[mf][g], 0, 0, 0);
                    acc[mf][g] = __builtin_amdgcn_mfma_f32_16x16x32_bf16(ahi, Wf[kk][g][1], acc[mf][g], 0, 0, 0);
                    acc[mf][g] = __builtin_amdgcn_mfma_f32_16x16x32_bf16(alo, Wf[kk][g][0], acc[mf][g], 0, 0, 0);
                }
            }
        }

        // ---- split-K tree reduction in LDS ----
        if (w >= 4) {
#pragma unroll
            for (int mf = 0; mf < 4; ++mf)
#pragma unroll
                for (int g = 0; g < 6; ++g)
                    *(f32x4*)&red[w - 4][mf][g][lane][0] = acc[mf][g];
        }
        __syncthreads();
        if (w < 4) {
#pragma unroll
            for (int mf = 0; mf < 4; ++mf)
#pragma unroll
                for (int g = 0; g < 6; ++g)
                    acc[mf][g] += *(const f32x4*)&red[w][mf][g][lane][0];
        }
        __syncthreads();
        if (w == 2 || w == 3) {
#pragma unroll
            for (int mf = 0; mf < 4; ++mf)
#pragma unroll
                for (int g = 0; g < 6; ++g)
                    *(f32x4*)&red[w - 2][mf][g][lane][0] = acc[mf][g];
        }
        __syncthreads();
        if (w < 2) {
#pragma unroll
            for (int mf = 0; mf < 4; ++mf)
#pragma unroll
                for (int g = 0; g < 6; ++g)
                    acc[mf][g] += *(const f32x4*)&red[w][mf][g][lane][0];
        }
        __syncthreads();
        if (w == 1) {
#pragma unroll
            for (int mf = 0; mf < 4; ++mf)
#pragma unroll
                for (int g = 0; g < 6; ++g)
                    *(f32x4*)&red[0][mf][g][lane][0] = acc[mf][g];
        }
        __syncthreads();
        if (w == 0) {
#pragma unroll
            for (int mf = 0; mf < 4; ++mf)
#pragma unroll
                for (int g = 0; g < 6; ++g) {
                    acc[mf][g] += *(const f32x4*)&red[0][mf][g][lane][0];
                    *(f32x4*)&red[1][mf][g][lane][0] = acc[mf][g];
                }
        }
        __syncthreads();

        // ---- epilogue: gate math, 2 outputs per thread ----
        {
            float v0[6], v1[6];
#pragma unroll
            for (int g = 0; g < 6; ++g) {
                v0[g] = red[1][emf][g][elane + ecol][ev];
                v1[g] = red[1][emf][g][elane + ecol + 1][ev];
            }
            size_t i0 = (size_t)gr * H_ + gc0;
            size_t i1 = (size_t)gr * H_ + gc1;
            float hp0 = bf2f(curHi[i0]) + bf2f(curLo[i0]);
            float hp1 = bf2f(curHi[i1]) + bf2f(curLo[i1]);

            float rg0 = 1.f / (1.f + expf(-((v0[0] + eb0[0]) + (v0[3] + eb0[3]))));
            float zg0 = 1.f / (1.f + expf(-((v0[1] + eb0[1]) + (v0[4] + eb0[4]))));
            float ng0 = tanhf((v0[2] + eb0[2]) + rg0 * (v0[5] + eb0[5]));
            float hn0 = (1.f - zg0) * ng0 + zg0 * hp0;

            float rg1 = 1.f / (1.f + expf(-((v1[0] + eb1[0]) + (v1[3] + eb1[3]))));
            float zg1 = 1.f / (1.f + expf(-((v1[1] + eb1[1]) + (v1[4] + eb1[4]))));
            float ng1 = tanhf((v1[2] + eb1[2]) + rg1 * (v1[5] + eb1[5]));
            float hn1 = (1.f - zg1) * ng1 + zg1 * hp1;

            short h0i = f2bf(hn0), h1i = f2bf(hn1);
            nxtHi[i0] = h0i; nxtLo[i0] = f2bf(hn0 - bf2f(h0i));
            nxtHi[i1] = h1i; nxtLo[i1] = f2bf(hn1 - bf2f(h1i));
            size_t oo = (size_t)gr * (TS_ * H_) + (size_t)t * H_;
            __builtin_nontemporal_store(hn0, &out[oo + gc0]);
            __builtin_nontemporal_store(hn1, &out[oo + gc1]);
        }

        __syncthreads();   // all stores issued & drained before release

        if (t < TS_ - 1) {
            if (tid == 0) {
                __hip_atomic_fetch_add(myctr, 1u, __ATOMIC_RELEASE, __HIP_MEMORY_SCOPE_AGENT);
                unsigned int target = 32u * (unsigned)(t + 1);
                while (__hip_atomic_load(myctr, __ATOMIC_RELAXED, __HIP_MEMORY_SCOPE_AGENT) < target)
                    __builtin_amdgcn_s_sleep(1);
                (void)__hip_atomic_load(myctr, __ATOMIC_ACQUIRE, __HIP_MEMORY_SCOPE_AGENT);
            }
            __syncthreads();
            const short* th = curHi; const short* tl = curLo;
            curHi = nxtHi; curLo = nxtLo;
            nxtHi = (short*)th; nxtLo = (short*)tl;
        }
    }
}

extern "C" void kernel_launch(void* const* d_in, const int* in_sizes, int n_in,
                              void* d_out, int out_size, void* d_ws, size_t ws_size,
                              hipStream_t stream) {
    const float* x     = (const float*)d_in[0];
    const float* W_lin = (const float*)d_in[1];
    const float* b_lin = (const float*)d_in[2];
    const float* W_ih  = (const float*)d_in[3];
    const float* W_hh  = (const float*)d_in[4];
    const float* b_ih  = (const float*)d_in[5];
    const float* b_hh  = (const float*)d_in[6];
    float* out = (float*)d_out;

    char* wsb = (char*)d_ws;
    short* Wpk2  = (short*)(wsb);                    // 6291456 B
    float* WlinT = (float*)(wsb + 6291456);          // 2097152 B
    float* bp    = (float*)(wsb + 8388608);          // 12288 B
    short* hHiA  = (short*)(wsb + 8400896);          // 524288 B
    short* hLoA  = (short*)(wsb + 8925184);
    short* hHiB  = (short*)(wsb + 9449472);
    short* hLoB  = (short*)(wsb + 9973760);
    unsigned int* ctr = (unsigned int*)(wsb + 10498048);  // 8 groups x 256 uints (1KB apart)

    hipMemcpyAsync(bp,        b_ih, 1536 * sizeof(float), hipMemcpyDeviceToDevice, stream);
    hipMemcpyAsync(bp + 1536, b_hh, 1536 * sizeof(float), hipMemcpyDeviceToDevice, stream);
    hipMemsetAsync(ctr, 0, 8 * 256 * sizeof(unsigned int), stream);

    pack_weights <<<dim3(32, 16), 384, 0, stream>>>(W_ih, W_hh, Wpk2);
    transpose_lin<<<dim3(16, 32), dim3(32, 8), 0, stream>>>(W_lin, WlinT);

    gemm_h0<<<dim3(16, 16), 256, 0, stream>>>(x, WlinT, b_lin, hHiA, hLoA);

    gru_persist<<<256, 512, 0, stream>>>(Wpk2, bp, hHiA, hLoA, hHiB, hLoB, out, ctr);
}

// Round 7
// 1145.019 us; speedup vs baseline: 2.2359x; 1.8424x over previous
//
#include <hip/hip_runtime.h>
#include <hip/hip_bf16.h>
#include <math.h>

#define B_   512
#define H_   512
#define FIN_ 1024
#define TS_  128

typedef __attribute__((ext_vector_type(8))) short short8;
typedef __attribute__((ext_vector_type(4))) float f32x4;

static __device__ __forceinline__ short f2bf(float f) {
    __hip_bfloat16 b = __float2bfloat16(f);
    return __builtin_bit_cast(short, b);
}
static __device__ __forceinline__ float bf2f(short s) {
    unsigned int u = ((unsigned int)(unsigned short)s) << 16;
    return __builtin_bit_cast(float, u);
}

// ---------------- weight prepack (once per call) ----------------
// Wpk2 fragment-packed bf16 pairs:
//   [jt 0..31][kt 0..15][g 0..5][sel 0..1 (hi/lo)][lane 0..63][i 0..7]
// B-frag (16x16x32): lane holds B[k = kt*32 + (lane>>4)*8 + i][j = jt*16 + (lane&15)]
__global__ __launch_bounds__(384)
void pack_weights(const float* __restrict__ Wih, const float* __restrict__ Whh,
                  short* __restrict__ Wpk2) {
    int jt = blockIdx.x;              // 0..31
    int kt = blockIdx.y;              // 0..15
    int g    = threadIdx.x >> 6;      // 0..5
    int lane = threadIdx.x & 63;
    int j = jt * 16 + (lane & 15);
    int k = kt * 32 + (lane >> 4) * 8;
    const float* src = (g < 3) ? &Wih[(size_t)(g * H_ + j) * H_ + k]
                               : &Whh[(size_t)((g - 3) * H_ + j) * H_ + k];
    short8 vhi, vlo;
#pragma unroll
    for (int i = 0; i < 8; ++i) {
        float w  = src[i];
        short hi = f2bf(w);
        vhi[i] = hi;
        vlo[i] = f2bf(w - bf2f(hi));
    }
    size_t base = ((((size_t)(jt * 16 + kt) * 6 + g) * 2) * 64 + lane) * 8;
    *reinterpret_cast<short8*>(&Wpk2[base])       = vhi;
    *reinterpret_cast<short8*>(&Wpk2[base + 512]) = vlo;
}

// WlinT[k][j] = W_lin[j][k], [1024][512]
__global__ void transpose_lin(const float* __restrict__ Wlin,
                              float* __restrict__ Wt) {
    __shared__ float t[32][33];
    int j0 = blockIdx.x * 32, k0 = blockIdx.y * 32;
    int kk = threadIdx.x, jj = threadIdx.y;
#pragma unroll
    for (int r = 0; r < 32; r += 8)
        t[jj + r][kk] = Wlin[(size_t)(j0 + jj + r) * FIN_ + k0 + kk];
    __syncthreads();
#pragma unroll
    for (int r = 0; r < 32; r += 8)
        Wt[(size_t)(k0 + jj + r) * H_ + j0 + kk] = t[kk][jj + r];
}

// ---------------- h0 = x @ WlinT + b_lin  (fp32, writes hi/lo bf16 split) ----------------
__global__ __launch_bounds__(256)
void gemm_h0(const float* __restrict__ X, const float* __restrict__ Wt,
             const float* __restrict__ bias,
             short* __restrict__ Hhi, short* __restrict__ Hlo) {
    const int BM = 32, BN = 32, BK = 32;
    __shared__ float xs[BK][BM + 2];
    __shared__ float ws[BK][BN];
    int b0 = blockIdx.y * BM, j0 = blockIdx.x * BN;
    int tid = threadIdx.x;
    int tx = tid & 15, ty = tid >> 4;
    float acc[2][2] = {};
    for (int k0 = 0; k0 < FIN_; k0 += BK) {
#pragma unroll
        for (int l = 0; l < 2; ++l) {
            int e = tid + l * 256;
            int krel = (e & 15) * 2, brel = e >> 4;
            float2 v = *(const float2*)&X[(size_t)(b0 + brel) * FIN_ + k0 + krel];
            xs[krel][brel] = v.x; xs[krel + 1][brel] = v.y;
        }
        {
            int fe = tid;
            int j4 = fe & 7, krel = fe >> 3;
            *(float4*)&ws[krel][j4 * 4] =
                *(const float4*)&Wt[(size_t)(k0 + krel) * H_ + j0 + j4 * 4];
        }
        __syncthreads();
#pragma unroll
        for (int kk = 0; kk < BK; ++kk) {
            float2 a = *(const float2*)&xs[kk][ty * 2];
            float2 w = *(const float2*)&ws[kk][tx * 2];
            acc[0][0] += a.x * w.x; acc[0][1] += a.x * w.y;
            acc[1][0] += a.y * w.x; acc[1][1] += a.y * w.y;
        }
        __syncthreads();
    }
#pragma unroll
    for (int r = 0; r < 2; ++r)
#pragma unroll
        for (int c = 0; c < 2; ++c) {
            int b = b0 + ty * 2 + r, j = j0 + tx * 2 + c;
            float v = acc[r][c] + bias[j];
            short hi = f2bf(v);
            Hhi[(size_t)b * H_ + j] = hi;
            Hlo[(size_t)b * H_ + j] = f2bf(v - bf2f(hi));
        }
}

// ---------------- persistent GRU: all 128 steps in one kernel ----------------
// 256 blocks (1/CU nominal, 2/CU resident), 512 threads (8 waves).
// Block = (row-group m = bid&7 -> 64 rows, jt = bid>>3 -> 16 cols).
// ALL h hi/lo traffic is nontemporal (bypasses L1/L2, lives at memory-side
// L3 = the cross-XCD coherence point) -> the group barrier needs NO cache
// maintenance: vmcnt-drain (via __syncthreads lowering) + RELAXED atomics.
// h_prev for the epilogue is carried in registers (thread owns fixed outputs).
__global__ __launch_bounds__(512, 2)
void gru_persist(const short* __restrict__ Wpk2,
                 const float* __restrict__ bp,
                 short* __restrict__ hHiA, short* __restrict__ hLoA,
                 short* __restrict__ hHiB, short* __restrict__ hLoB,
                 float* __restrict__ out,
                 unsigned int* __restrict__ ctr) {
    int bid  = blockIdx.x;
    int m    = bid & 7;            // row group (8 groups x 64 rows)
    int jt   = bid >> 3;           // 0..31
    int m0   = m * 64;
    int tid  = threadIdx.x;
    int w    = tid >> 6;           // wave 0..7
    int lane = tid & 63;

    unsigned int* myctr = ctr + m * 256;   // 1024B-spaced counters

    __shared__ float red[4][4][6][64][4];   // 4 bufs x 24 KB = 96 KB

    // ---- prologue: persistent W fragments ----
    short8 Wf[2][6][2];
#pragma unroll
    for (int kk = 0; kk < 2; ++kk) {
        int kt = 2 * w + kk;
        const short* wb = &Wpk2[((size_t)(jt * 16 + kt) * 6) * 1024 + lane * 8];
#pragma unroll
        for (int g = 0; g < 6; ++g) {
            Wf[kk][g][0] = *(const short8*)&wb[(size_t)g * 1024];
            Wf[kk][g][1] = *(const short8*)&wb[(size_t)g * 1024 + 512];
        }
    }

    // ---- epilogue mapping: thread owns 2 outputs (same row, adjacent cols) ----
    int o0   = tid * 2;
    int erow = o0 >> 4;            // 0..63 block-local row
    int ecol = o0 & 15;            // even col 0..14
    int gr   = m0 + erow;          // global row
    int gc0  = jt * 16 + ecol, gc1 = gc0 + 1;
    float eb0[6], eb1[6];
#pragma unroll
    for (int g = 0; g < 6; ++g) { eb0[g] = bp[g * H_ + gc0]; eb1[g] = bp[g * H_ + gc1]; }
    int emf   = erow >> 4;
    int elane = ((erow & 15) >> 2) << 4;
    int ev    = erow & 3;

    size_t i0 = (size_t)gr * H_ + gc0;
    size_t i1 = (size_t)gr * H_ + gc1;
    // h_prev carried in registers (initial h0 from gemm_h0 output)
    float hp0 = bf2f(hHiA[i0]) + bf2f(hLoA[i0]);
    float hp1 = bf2f(hHiA[i1]) + bf2f(hLoA[i1]);

    const short* curHi = hHiA; const short* curLo = hLoA;
    short* nxtHi = hHiB; short* nxtLo = hLoB;

    int arow  = m0 + (lane & 15);
    int akoff = (lane >> 4) * 8;

    for (int t = 0; t < TS_; ++t) {
        f32x4 acc[4][6] = {};
#pragma unroll
        for (int kk = 0; kk < 2; ++kk) {
            int kbase = (2 * w + kk) * 32 + akoff;
#pragma unroll
            for (int mf = 0; mf < 4; ++mf) {
                size_t aoff = (size_t)(arow + 16 * mf) * H_ + kbase;
                short8 ahi = __builtin_nontemporal_load((const short8*)&curHi[aoff]);
                short8 alo = __builtin_nontemporal_load((const short8*)&curLo[aoff]);
                if (t > 0) {
#pragma unroll
                    for (int g = 0; g < 3; ++g) {
                        acc[mf][g] = __builtin_amdgcn_mfma_f32_16x16x32_bf16(ahi, Wf[kk][g][0], acc[mf][g], 0, 0, 0);
                        acc[mf][g] = __builtin_amdgcn_mfma_f32_16x16x32_bf16(ahi, Wf[kk][g][1], acc[mf][g], 0, 0, 0);
                        acc[mf][g] = __builtin_amdgcn_mfma_f32_16x16x32_bf16(alo, Wf[kk][g][0], acc[mf][g], 0, 0, 0);
                    }
                }
#pragma unroll
                for (int g = 3; g < 6; ++g) {
                    acc[mf][g] = __builtin_amdgcn_mfma_f32_16x16x32_bf16(ahi, Wf[kk][g][0], acc[mf][g], 0, 0, 0);
                    acc[mf][g] = __builtin_amdgcn_mfma_f32_16x16x32_bf16(ahi, Wf[kk][g][1], acc[mf][g], 0, 0, 0);
                    acc[mf][g] = __builtin_amdgcn_mfma_f32_16x16x32_bf16(alo, Wf[kk][g][0], acc[mf][g], 0, 0, 0);
                }
            }
        }

        // ---- split-K tree reduction in LDS ----
        if (w >= 4) {
#pragma unroll
            for (int mf = 0; mf < 4; ++mf)
#pragma unroll
                for (int g = 0; g < 6; ++g)
                    *(f32x4*)&red[w - 4][mf][g][lane][0] = acc[mf][g];
        }
        __syncthreads();
        if (w < 4) {
#pragma unroll
            for (int mf = 0; mf < 4; ++mf)
#pragma unroll
                for (int g = 0; g < 6; ++g)
                    acc[mf][g] += *(const f32x4*)&red[w][mf][g][lane][0];
        }
        __syncthreads();
        if (w == 2 || w == 3) {
#pragma unroll
            for (int mf = 0; mf < 4; ++mf)
#pragma unroll
                for (int g = 0; g < 6; ++g)
                    *(f32x4*)&red[w - 2][mf][g][lane][0] = acc[mf][g];
        }
        __syncthreads();
        if (w < 2) {
#pragma unroll
            for (int mf = 0; mf < 4; ++mf)
#pragma unroll
                for (int g = 0; g < 6; ++g)
                    acc[mf][g] += *(const f32x4*)&red[w][mf][g][lane][0];
        }
        __syncthreads();
        if (w == 1) {
#pragma unroll
            for (int mf = 0; mf < 4; ++mf)
#pragma unroll
                for (int g = 0; g < 6; ++g)
                    *(f32x4*)&red[0][mf][g][lane][0] = acc[mf][g];
        }
        __syncthreads();
        if (w == 0) {
#pragma unroll
            for (int mf = 0; mf < 4; ++mf)
#pragma unroll
                for (int g = 0; g < 6; ++g) {
                    acc[mf][g] += *(const f32x4*)&red[0][mf][g][lane][0];
                    *(f32x4*)&red[1][mf][g][lane][0] = acc[mf][g];
                }
        }
        __syncthreads();

        // ---- epilogue: gate math, 2 outputs per thread, hp in registers ----
        {
            float v0[6], v1[6];
#pragma unroll
            for (int g = 0; g < 6; ++g) {
                v0[g] = red[1][emf][g][elane + ecol][ev];
                v1[g] = red[1][emf][g][elane + ecol + 1][ev];
            }
            float rg0 = 1.f / (1.f + expf(-((v0[0] + eb0[0]) + (v0[3] + eb0[3]))));
            float zg0 = 1.f / (1.f + expf(-((v0[1] + eb0[1]) + (v0[4] + eb0[4]))));
            float ng0 = tanhf((v0[2] + eb0[2]) + rg0 * (v0[5] + eb0[5]));
            float hn0 = (1.f - zg0) * ng0 + zg0 * hp0;

            float rg1 = 1.f / (1.f + expf(-((v1[0] + eb1[0]) + (v1[3] + eb1[3]))));
            float zg1 = 1.f / (1.f + expf(-((v1[1] + eb1[1]) + (v1[4] + eb1[4]))));
            float ng1 = tanhf((v1[2] + eb1[2]) + rg1 * (v1[5] + eb1[5]));
            float hn1 = (1.f - zg1) * ng1 + zg1 * hp1;

            short h0i = f2bf(hn0), h1i = f2bf(hn1);
            __builtin_nontemporal_store(h0i, &nxtHi[i0]);
            __builtin_nontemporal_store(f2bf(hn0 - bf2f(h0i)), &nxtLo[i0]);
            __builtin_nontemporal_store(h1i, &nxtHi[i1]);
            __builtin_nontemporal_store(f2bf(hn1 - bf2f(h1i)), &nxtLo[i1]);
            size_t oo = (size_t)gr * (TS_ * H_) + (size_t)t * H_;
            __builtin_nontemporal_store(hn0, &out[oo + gc0]);
            __builtin_nontemporal_store(hn1, &out[oo + gc1]);
            hp0 = hn0; hp1 = hn1;
        }

        if (t < TS_ - 1) {
            __syncthreads();   // drains vmcnt for all waves' nt stores
            if (tid == 0) {
                asm volatile("s_waitcnt vmcnt(0)" ::: "memory");
                __hip_atomic_fetch_add(myctr, 1u, __ATOMIC_RELAXED, __HIP_MEMORY_SCOPE_AGENT);
                unsigned int target = 32u * (unsigned)(t + 1);
                while (__hip_atomic_load(myctr, __ATOMIC_RELAXED, __HIP_MEMORY_SCOPE_AGENT) < target)
                    __builtin_amdgcn_s_sleep(1);
            }
            __syncthreads();
            asm volatile("" ::: "memory");
            const short* th = curHi; const short* tl = curLo;
            curHi = nxtHi; curLo = nxtLo;
            nxtHi = (short*)th; nxtLo = (short*)tl;
        }
    }
}

extern "C" void kernel_launch(void* const* d_in, const int* in_sizes, int n_in,
                              void* d_out, int out_size, void* d_ws, size_t ws_size,
                              hipStream_t stream) {
    const float* x     = (const float*)d_in[0];
    const float* W_lin = (const float*)d_in[1];
    const float* b_lin = (const float*)d_in[2];
    const float* W_ih  = (const float*)d_in[3];
    const float* W_hh  = (const float*)d_in[4];
    const float* b_ih  = (const float*)d_in[5];
    const float* b_hh  = (const float*)d_in[6];
    float* out = (float*)d_out;

    char* wsb = (char*)d_ws;
    short* Wpk2  = (short*)(wsb);                    // 6291456 B
    float* WlinT = (float*)(wsb + 6291456);          // 2097152 B
    float* bp    = (float*)(wsb + 8388608);          // 12288 B
    short* hHiA  = (short*)(wsb + 8400896);          // 524288 B
    short* hLoA  = (short*)(wsb + 8925184);
    short* hHiB  = (short*)(wsb + 9449472);
    short* hLoB  = (short*)(wsb + 9973760);
    unsigned int* ctr = (unsigned int*)(wsb + 10498048);  // 8 groups x 256 uints

    hipMemcpyAsync(bp,        b_ih, 1536 * sizeof(float), hipMemcpyDeviceToDevice, stream);
    hipMemcpyAsync(bp + 1536, b_hh, 1536 * sizeof(float), hipMemcpyDeviceToDevice, stream);
    hipMemsetAsync(ctr, 0, 8 * 256 * sizeof(unsigned int), stream);

    pack_weights <<<dim3(32, 16), 384, 0, stream>>>(W_ih, W_hh, Wpk2);
    transpose_lin<<<dim3(16, 32), dim3(32, 8), 0, stream>>>(W_lin, WlinT);

    gemm_h0<<<dim3(16, 16), 256, 0, stream>>>(x, WlinT, b_lin, hHiA, hLoA);

    gru_persist<<<256, 512, 0, stream>>>(Wpk2, bp, hHiA, hLoA, hHiB, hLoB, out, ctr);
}